// Round 1
// baseline (677.228 us; speedup 1.0000x reference)
//
#include <hip/hip_runtime.h>
#include <hip/hip_bf16.h>

// Problem: B=8, T_OUT=256, T_IN=512, L=128, D_IN=128, D_ATT=128 (f32 in/out).
// R8: FUSION round. Attention is restructured as consumer blocks inside the
// scan launch (blocks 2..513), spin-waiting on a progress flag the scan
// publishes every 8 steps. The 254 CUs that idled for 150us now do the
// ~150us of attention work under the scan's shadow; only the last q-chunks
// (~15us) run after the scan finishes. keys moves to the prologue launch and
// is stored TRANSPOSED (keysT[b][l][k]) for coalesced score reads.
// Scan micro-fix: hb stride 136 -> 144 (4-way -> 2-way/free bank pattern on
// both ds_read_b128 B-frags and h-writes; was 144 conflict-cycles/step).
//
// Deadlock safety is by CAPACITY, not dispatch order: grid=514 blocks,
// __launch_bounds__(512,6) => VGPR<=85, LDS 29.3KB/block => 3 blocks/CU
// guaranteed => all 514 blocks co-resident; scan blocks always run.
//
// Cross-XCD coherence: x rows stored f32 via agent-scope relaxed atomic
// stores (write-through to coherence point); publication = full
// __syncthreads() (drains vmcnt for ALL waves) then tid0 agent-scope flag
// store. Consumers poll agent-scope atomic loads, then agent-scope-load x.
// No release/acquire fences => no L2 invalidations => keysT/attended stay
// L2-cached. prog[] is zeroed by the prologue launch each iteration (stream
// order guarantees it precedes the fused kernel).
//
// ws layout (float elements):
#define XF_OFF   0         // f32 x[8*256*128] (262144 floats)
#define PROG_OFF 524288    // int prog[2] (in otherwise-unused region)
#define XZ_OFF   1048576   // f16[8*256*512] region (2 MB)
#define KEYS_OFF 2097152   // f32 keysT[8][128][512]
// out layout (f32): out(8,256,256) @0, h(8,128) @524288, c(8,128) @525312
#define OUT_H    524288
#define OUT_C    525312

#define LDS_BARRIER() __asm__ __volatile__("s_waitcnt lgkmcnt(0)\n\ts_barrier" ::: "memory")

typedef _Float16 f16x8 __attribute__((ext_vector_type(8)));
typedef float fx4 __attribute__((ext_vector_type(4)));

__device__ __forceinline__ float fast_rcp(float x) { return __builtin_amdgcn_rcpf(x); }
__device__ __forceinline__ float fast_sig(float v) { return fast_rcp(1.f + __expf(-v)); }
__device__ __forceinline__ float fast_tanh(float v) { return 2.f * fast_rcp(1.f + __expf(-2.f * v)) - 1.f; }

// ---------------- Kernel 1: xz prologue (blocks 0-255) + keysT GEMM (256-511) ----------------
__global__ __launch_bounds__(256)
void prologue_k(const float* __restrict__ inp, const float* __restrict__ Wk,
                const float* __restrict__ bias, const float* __restrict__ att,
                const float* __restrict__ W1, const float* __restrict__ b1,
                float* __restrict__ ws) {
  __shared__ float ar[8][128];
  __shared__ float ar2[16][128];
  const int tid = threadIdx.x;

  if (blockIdx.x < 256) {
    // ---- xz = inputs @ Wk + bias, f16 [t][b][u][gate] ----
    _Float16* xz16 = (_Float16*)(ws + XZ_OFF);
    const int row0 = blockIdx.x * 8;
    for (int i = tid; i < 8 * 128; i += 256) ar[i >> 7][i & 127] = inp[row0 * 128 + i];
    __syncthreads();
    float acc[8][2];
    const float bb0 = bias[tid], bb1 = bias[tid + 256];
#pragma unroll
    for (int r = 0; r < 8; ++r) { acc[r][0] = bb0; acc[r][1] = bb1; }
    for (int d = 0; d < 128; d += 4) {
      float w0a = Wk[(d + 0) * 512 + tid], w0b = Wk[(d + 0) * 512 + tid + 256];
      float w1a = Wk[(d + 1) * 512 + tid], w1b = Wk[(d + 1) * 512 + tid + 256];
      float w2a = Wk[(d + 2) * 512 + tid], w2b = Wk[(d + 2) * 512 + tid + 256];
      float w3a = Wk[(d + 3) * 512 + tid], w3b = Wk[(d + 3) * 512 + tid + 256];
#pragma unroll
      for (int r = 0; r < 8; ++r) {
        float4 a4 = *(const float4*)&ar[r][d];
        acc[r][0] += a4.x * w0a + a4.y * w1a + a4.z * w2a + a4.w * w3a;
        acc[r][1] += a4.x * w0b + a4.y * w1b + a4.z * w2b + a4.w * w3b;
      }
    }
    const int u = tid & 127, g0 = tid >> 7;
#pragma unroll
    for (int r = 0; r < 8; ++r) {
      const int row = row0 + r, b = row >> 8, t = row & 255;
      const int base = ((t * 8 + b) * 128 + u) * 4;
      xz16[base + g0]     = (_Float16)acc[r][0];
      xz16[base + g0 + 2] = (_Float16)acc[r][1];
    }
    return;
  }

  // ---- keysT[b][l][k] = (attended @ W1 + b1)^T : 16 k-rows per block ----
  // Each thread computes 8 CONSECUTIVE k for its l => two float4 stores.
  if (blockIdx.x == 256 && tid < 2) ((int*)(ws + PROG_OFF))[tid] = 0;  // reset flags each iteration
  const int kb = blockIdx.x - 256;
  const int row0 = kb * 16;              // global row in (b*512 + k)
  const int bq = row0 >> 9, k0 = row0 & 511;
  for (int i = tid; i < 16 * 128; i += 256) ar2[i >> 7][i & 127] = att[row0 * 128 + i];
  __syncthreads();
  const int l = tid & 127, r0 = tid >> 7;  // r0 in 0..1
  float acc[8];
  const float bl = b1[l];
#pragma unroll
  for (int i = 0; i < 8; ++i) acc[i] = bl;
  for (int d = 0; d < 128; d += 4) {
    float w0 = W1[(d + 0) * 128 + l], w1 = W1[(d + 1) * 128 + l];
    float w2 = W1[(d + 2) * 128 + l], w3 = W1[(d + 3) * 128 + l];
#pragma unroll
    for (int i = 0; i < 8; ++i) {
      float4 a4 = *(const float4*)&ar2[r0 * 8 + i][d];
      acc[i] += a4.x * w0 + a4.y * w1 + a4.z * w2 + a4.w * w3;
    }
  }
  float* kT = ws + KEYS_OFF + (bq * 128 + l) * 512 + k0 + r0 * 8;
  float4 lo = {acc[0], acc[1], acc[2], acc[3]};
  float4 hi = {acc[4], acc[5], acc[6], acc[7]};
  *(float4*)kT = lo;
  *(float4*)(kT + 4) = hi;
}

// ---------------- Kernel 2: fused LSTM scan (blocks 0-1) + attention (blocks 2-513) ----------------
struct ScanS { _Float16 hb[2][576]; };                       // 2.25 KB
struct AttnS {                                               // 29312 B total
  float xr[4][128];       // staged x rows
  float qp[4][128];       // q projection
  float sc[4][512];       // scores -> probs
  float kc[8][516];       // keysT chunk (8 l-rows x 512 k, pad 4)
  float w3s[128];
};

__global__ __launch_bounds__(512, 6)
void fused_scan_attn(const float* __restrict__ Wrf, const float* __restrict__ att,
                     const float* __restrict__ W2c, const float* __restrict__ b2c,
                     const float* __restrict__ W3c, const float* __restrict__ b3c,
                     float* __restrict__ ws, float* __restrict__ out) {
  __shared__ __align__(16) char smem[29312];
  const int tid = threadIdx.x;
  int* prog = (int*)(ws + PROG_OFF);
  float* xf = ws + XF_OFF;

  if (blockIdx.x >= 2) {
    // ================= attention consumer =================
    AttnS* A = (AttnS*)smem;
    const int a = blockIdx.x - 2;
    const int b = a >> 6, q0 = (a & 63) * 4;   // natural order puts late q0 on the scan CUs' 2nd/3rd slots
    const int l = tid & 127, r0 = tid >> 7;    // one thread per (row, l)
    if (tid < 128) A->w3s[tid] = W3c[tid];
    if (tid == 0) {
      while (__hip_atomic_load(&prog[b >> 2], __ATOMIC_RELAXED, __HIP_MEMORY_SCOPE_AGENT) < q0 + 4)
        __builtin_amdgcn_s_sleep(16);
    }
    __syncthreads();
    const int row = b * 256 + q0 + r0;
    const float xv = __hip_atomic_load(&xf[row * 128 + l], __ATOMIC_RELAXED, __HIP_MEMORY_SCOPE_AGENT);
    A->xr[r0][l] = xv;
    out[row * 256 + l] = xv;
    __syncthreads();
    // ---- qproj: qp[r0][l] ----
    float qa = b2c[l];
    for (int d = 0; d < 128; d += 4) {
      float4 x4 = *(const float4*)&A->xr[r0][d];
      qa += x4.x * W2c[(d + 0) * 128 + l] + x4.y * W2c[(d + 1) * 128 + l]
          + x4.z * W2c[(d + 2) * 128 + l] + x4.w * W2c[(d + 3) * 128 + l];
    }
    A->qp[r0][l] = qa;
    const float b3v = b3c[0];
    // ---- scores: thread owns k = l + 128j, j=0..3 ----
    float acc0 = b3v, acc1 = b3v, acc2 = b3v, acc3 = b3v;
    const float* keysT = ws + KEYS_OFF + b * (128 * 512);
    for (int c = 0; c < 128; c += 8) {
      __syncthreads();   // kc reuse fence (1st iter: also publishes qp)
      for (int i = tid; i < 8 * 512; i += 512)
        A->kc[i >> 9][i & 511] = keysT[(c + (i >> 9)) * 512 + (i & 511)];
      __syncthreads();
      for (int lp = 0; lp < 8; ++lp) {
        const float qv = A->qp[r0][c + lp];   // broadcast
        const float wv = A->w3s[c + lp];      // broadcast
        acc0 += fast_tanh(A->kc[lp][l]       + qv) * wv;
        acc1 += fast_tanh(A->kc[lp][l + 128] + qv) * wv;
        acc2 += fast_tanh(A->kc[lp][l + 256] + qv) * wv;
        acc3 += fast_tanh(A->kc[lp][l + 384] + qv) * wv;
      }
    }
    A->sc[r0][l]       = acc0;
    A->sc[r0][l + 128] = acc1;
    A->sc[r0][l + 256] = acc2;
    A->sc[r0][l + 384] = acc3;
    __syncthreads();
    // ---- softmax: wave w owns row w (waves 4-7 idle briefly) ----
    {
      const int wave = tid >> 6, lane = tid & 63;
      if (wave < 4) {
        float v[8];
#pragma unroll
        for (int i = 0; i < 8; ++i) v[i] = A->sc[wave][lane + i * 64];
        float m = v[0];
#pragma unroll
        for (int i = 1; i < 8; ++i) m = fmaxf(m, v[i]);
#pragma unroll
        for (int off = 32; off > 0; off >>= 1) m = fmaxf(m, __shfl_xor(m, off));
        float e[8], s = 0.f;
#pragma unroll
        for (int i = 0; i < 8; ++i) { e[i] = __expf(v[i] - m); s += e[i]; }
#pragma unroll
        for (int off = 32; off > 0; off >>= 1) s += __shfl_xor(s, off);
        const float inv = fast_rcp(s);
#pragma unroll
        for (int i = 0; i < 8; ++i) A->sc[wave][lane + i * 64] = e[i] * inv;
      }
    }
    __syncthreads();
    // ---- weighted sum + concat ----
    const float* attb = att + b * (512 * 128);
    float wa = 0.f;
    for (int k = 0; k < 512; k += 4) {
      float4 p4 = *(const float4*)&A->sc[r0][k];
      wa += p4.x * attb[(k + 0) * 128 + l] + p4.y * attb[(k + 1) * 128 + l]
          + p4.z * attb[(k + 2) * 128 + l] + p4.w * attb[(k + 3) * 128 + l];
    }
    out[row * 256 + 128 + l] = wa;
    return;
  }

  // ================= LSTM scan producer =================
  ScanS* S = (ScanS*)smem;
  const _Float16* xz16 = (const _Float16*)(ws + XZ_OFF);
  const int b_base = blockIdx.x * 4;
  const int w = tid >> 6, lane = tid & 63;
  const int q = lane >> 4, p = lane & 15;
  const int b = p & 3, isel = p >> 2;
  const int u = 16 * w + 4 * isel + q;
  const int bg = b_base + b;

  f16x8 afr[4][4];
#pragma unroll
  for (int i = 0; i < 4; ++i) {
    const int col = (p & 3) * 128 + 16 * w + 4 * i + (p >> 2);
#pragma unroll
    for (int kt = 0; kt < 4; ++kt)
#pragma unroll
      for (int j = 0; j < 8; ++j)
        afr[i][kt][j] = (_Float16)Wrf[(kt * 32 + q * 8 + j) * 512 + col];
  }
  {
    _Float16* hp = &S->hb[0][0];
    for (int i = tid; i < 2 * 576; i += 512) hp[i] = (_Float16)0.f;
  }
  const fx4 zeroC = {0.f, 0.f, 0.f, 0.f};
  float cst = 0.f, hval = 0.f;
  const _Float16* xp = xz16 + (bg * 128 + u) * 4;
  uint2 pf0 = *(const uint2*)(xp);
  uint2 pf1 = *(const uint2*)(xp + 4096);
  uint2 pf2 = *(const uint2*)(xp + 8192);
  __syncthreads();

  const int brow = b * 144;  // stride 144: banks 8b+4q(+2isel) -> perfect 2-way (free)
  for (int t = 0; t < 256; ++t) {
    const _Float16* hrow = &S->hb[t & 1][brow];
    f16x8 bfr[4];
#pragma unroll
    for (int kt = 0; kt < 4; ++kt)
      bfr[kt] = *(const f16x8*)&hrow[kt * 32 + q * 8];
    fx4 acc[4];
#pragma unroll
    for (int i = 0; i < 4; ++i)
      acc[i] = __builtin_amdgcn_mfma_f32_16x16x32_f16(afr[i][0], bfr[0], zeroC, 0, 0, 0);
#pragma unroll
    for (int kt = 1; kt < 4; ++kt)
#pragma unroll
      for (int i = 0; i < 4; ++i)
        acc[i] = __builtin_amdgcn_mfma_f32_16x16x32_f16(afr[i][kt], bfr[kt], acc[i], 0, 0, 0);

    float z[4];
#pragma unroll
    for (int r = 0; r < 4; ++r) {
      float s01 = (isel & 1) ? acc[1][r] : acc[0][r];
      float s23 = (isel & 1) ? acc[3][r] : acc[2][r];
      z[r] = (isel & 2) ? s23 : s01;
    }

    uint2 cur = pf0;
    pf0 = pf1; pf1 = pf2;

    const _Float16* cf = (const _Float16*)&cur;
    const float zi = z[0] + (float)cf[0];
    const float zf = z[1] + (float)cf[1];
    const float zg = z[2] + (float)cf[2];
    const float zo = z[3] + (float)cf[3];
    cst = fast_sig(zf) * cst + fast_sig(zi) * fast_tanh(zg);
    hval = fast_sig(zo) * fast_tanh(cst);
    S->hb[(t + 1) & 1][brow + u] = (_Float16)hval;
    // agent-scope write-through so consumers on other XCDs see fresh data
    __hip_atomic_store(&xf[(bg * 256 + t) * 128 + u], hval,
                       __ATOMIC_RELAXED, __HIP_MEMORY_SCOPE_AGENT);

    if ((t & 7) == 7) {
      __syncthreads();  // drains vmcnt(0) for ALL waves -> x rows <= t globally visible
      if (tid == 0)
        __hip_atomic_store(&prog[blockIdx.x], t + 1,
                           __ATOMIC_RELAXED, __HIP_MEMORY_SCOPE_AGENT);
    } else {
      LDS_BARRIER();  // LDS visibility only; no vmcnt drain
    }
    // issue prefetch AFTER the barrier so publication vmcnt(0) doesn't wait on it
    const int t3 = (t + 3 < 256) ? t + 3 : 255;
    pf2 = *(const uint2*)(xp + t3 * 4096);
  }
  out[OUT_H + bg * 128 + u] = hval;
  out[OUT_C + bg * 128 + u] = cst;
}

extern "C" void kernel_launch(void* const* d_in, const int* in_sizes, int n_in,
                              void* d_out, int out_size, void* d_ws, size_t ws_size,
                              hipStream_t stream) {
  const float* inputs   = (const float*)d_in[0];
  const float* attended = (const float*)d_in[1];
  const float* Wk       = (const float*)d_in[2];
  const float* Wr       = (const float*)d_in[3];
  const float* bias     = (const float*)d_in[4];
  const float* W1       = (const float*)d_in[5];
  const float* b1       = (const float*)d_in[6];
  const float* W2       = (const float*)d_in[7];
  const float* b2       = (const float*)d_in[8];
  const float* W3       = (const float*)d_in[9];
  const float* b3       = (const float*)d_in[10];
  float* out = (float*)d_out;
  float* ws = (float*)d_ws;

  hipLaunchKernelGGL(prologue_k, dim3(512), dim3(256), 0, stream,
                     inputs, Wk, bias, attended, W1, b1, ws);
  hipLaunchKernelGGL(fused_scan_attn, dim3(514), dim3(512), 0, stream,
                     Wr, attended, W2, b2, W3, b3, ws, out);
}

// Round 2
// 345.086 us; speedup vs baseline: 1.9625x; 1.9625x over previous
//
#include <hip/hip_runtime.h>
#include <hip/hip_bf16.h>

// Problem: B=8, T_OUT=256, T_IN=512, L=128, D_IN=128, D_ATT=128 (f32 in/out).
// R9: fusion kept, spill removed. R8's launch_bounds(512,6) capped VGPR at 85
// and spilled the scan's 64-VGPR Wr fragment set to scratch (FETCH_SIZE 2.6MB
// -> 69MB == 1024 thr x 256 steps x 256B reload; scan 150 -> 600us). R9 drops
// the cap entirely and restores safety structurally:
//   - grid 258 = 2 scan + 256 workers; worker w serially does chunks {2w,2w+1}
//     (same b, q0/q0+4). At worst-case 1 block/CU, 256 blocks are resident;
//     workers 0..127 need only scan block 0, 128..255 only block 1, so one
//     resident scan block drains half the workers and frees slots. No
//     capacity squeeze needed.
//   - scan publishes prog every 16 steps (half the vmcnt(0) drain barriers).
// Scan keeps R8's hb stride 144 (bank conflicts 73728 -> 0, verified).
//
// Cross-XCD coherence (unchanged from R8, which PASSED): x stored f32 via
// agent-scope relaxed atomic stores; publication = __syncthreads() (drains
// vmcnt for all waves) then tid0 agent-scope flag store. Consumers poll
// agent-scope, read x agent-scope. prog[] reset by prologue each iteration.
//
// ws layout (float elements):
#define XF_OFF   0         // f32 x[8*256*128]
#define PROG_OFF 524288    // int prog[2]
#define XZ_OFF   1048576   // f16[8*256*512] region (2 MB)
#define KEYS_OFF 2097152   // f32 keysT[8][128][512]
// out layout (f32): out(8,256,256) @0, h(8,128) @524288, c(8,128) @525312
#define OUT_H    524288
#define OUT_C    525312

#define LDS_BARRIER() __asm__ __volatile__("s_waitcnt lgkmcnt(0)\n\ts_barrier" ::: "memory")

typedef _Float16 f16x8 __attribute__((ext_vector_type(8)));
typedef float fx4 __attribute__((ext_vector_type(4)));

__device__ __forceinline__ float fast_rcp(float x) { return __builtin_amdgcn_rcpf(x); }
__device__ __forceinline__ float fast_sig(float v) { return fast_rcp(1.f + __expf(-v)); }
__device__ __forceinline__ float fast_tanh(float v) { return 2.f * fast_rcp(1.f + __expf(-2.f * v)) - 1.f; }

// ---------------- Kernel 1: xz prologue (blocks 0-255) + keysT GEMM (256-511) ----------------
__global__ __launch_bounds__(256)
void prologue_k(const float* __restrict__ inp, const float* __restrict__ Wk,
                const float* __restrict__ bias, const float* __restrict__ att,
                const float* __restrict__ W1, const float* __restrict__ b1,
                float* __restrict__ ws) {
  __shared__ float ar[8][128];
  __shared__ float ar2[16][128];
  const int tid = threadIdx.x;

  if (blockIdx.x < 256) {
    // ---- xz = inputs @ Wk + bias, f16 [t][b][u][gate] ----
    _Float16* xz16 = (_Float16*)(ws + XZ_OFF);
    const int row0 = blockIdx.x * 8;
    for (int i = tid; i < 8 * 128; i += 256) ar[i >> 7][i & 127] = inp[row0 * 128 + i];
    __syncthreads();
    float acc[8][2];
    const float bb0 = bias[tid], bb1 = bias[tid + 256];
#pragma unroll
    for (int r = 0; r < 8; ++r) { acc[r][0] = bb0; acc[r][1] = bb1; }
    for (int d = 0; d < 128; d += 4) {
      float w0a = Wk[(d + 0) * 512 + tid], w0b = Wk[(d + 0) * 512 + tid + 256];
      float w1a = Wk[(d + 1) * 512 + tid], w1b = Wk[(d + 1) * 512 + tid + 256];
      float w2a = Wk[(d + 2) * 512 + tid], w2b = Wk[(d + 2) * 512 + tid + 256];
      float w3a = Wk[(d + 3) * 512 + tid], w3b = Wk[(d + 3) * 512 + tid + 256];
#pragma unroll
      for (int r = 0; r < 8; ++r) {
        float4 a4 = *(const float4*)&ar[r][d];
        acc[r][0] += a4.x * w0a + a4.y * w1a + a4.z * w2a + a4.w * w3a;
        acc[r][1] += a4.x * w0b + a4.y * w1b + a4.z * w2b + a4.w * w3b;
      }
    }
    const int u = tid & 127, g0 = tid >> 7;
#pragma unroll
    for (int r = 0; r < 8; ++r) {
      const int row = row0 + r, b = row >> 8, t = row & 255;
      const int base = ((t * 8 + b) * 128 + u) * 4;
      xz16[base + g0]     = (_Float16)acc[r][0];
      xz16[base + g0 + 2] = (_Float16)acc[r][1];
    }
    return;
  }

  // ---- keysT[b][l][k] = (attended @ W1 + b1)^T : 16 k-rows per block ----
  if (blockIdx.x == 256 && tid < 2) ((int*)(ws + PROG_OFF))[tid] = 0;  // reset flags each iteration
  const int kb = blockIdx.x - 256;
  const int row0 = kb * 16;              // global row in (b*512 + k)
  const int bq = row0 >> 9, k0 = row0 & 511;
  for (int i = tid; i < 16 * 128; i += 256) ar2[i >> 7][i & 127] = att[row0 * 128 + i];
  __syncthreads();
  const int l = tid & 127, r0 = tid >> 7;  // r0 in 0..1
  float acc[8];
  const float bl = b1[l];
#pragma unroll
  for (int i = 0; i < 8; ++i) acc[i] = bl;
  for (int d = 0; d < 128; d += 4) {
    float w0 = W1[(d + 0) * 128 + l], w1 = W1[(d + 1) * 128 + l];
    float w2 = W1[(d + 2) * 128 + l], w3 = W1[(d + 3) * 128 + l];
#pragma unroll
    for (int i = 0; i < 8; ++i) {
      float4 a4 = *(const float4*)&ar2[r0 * 8 + i][d];
      acc[i] += a4.x * w0 + a4.y * w1 + a4.z * w2 + a4.w * w3;
    }
  }
  float* kT = ws + KEYS_OFF + (bq * 128 + l) * 512 + k0 + r0 * 8;
  float4 lo = {acc[0], acc[1], acc[2], acc[3]};
  float4 hi = {acc[4], acc[5], acc[6], acc[7]};
  *(float4*)kT = lo;
  *(float4*)(kT + 4) = hi;
}

// ---------------- Kernel 2: fused LSTM scan (blocks 0-1) + attention (blocks 2-257) ----------------
struct ScanS { _Float16 hb[2][576]; };                       // 2.25 KB
struct AttnS {                                               // 29312 B total
  float xr[4][128];       // staged x rows
  float qp[4][128];       // q projection
  float sc[4][512];       // scores -> probs
  float kc[8][516];       // keysT chunk (8 l-rows x 512 k, pad 4)
  float w3s[128];
};

__global__ __launch_bounds__(512)
void fused_scan_attn(const float* __restrict__ Wrf, const float* __restrict__ att,
                     const float* __restrict__ W2c, const float* __restrict__ b2c,
                     const float* __restrict__ W3c, const float* __restrict__ b3c,
                     float* __restrict__ ws, float* __restrict__ out) {
  __shared__ __align__(16) char smem[29312];
  const int tid = threadIdx.x;
  int* prog = (int*)(ws + PROG_OFF);
  float* xf = ws + XF_OFF;

  if (blockIdx.x >= 2) {
    // ================= attention consumer: worker w does chunks 2w, 2w+1 =================
    AttnS* A = (AttnS*)smem;
    const int wkr = blockIdx.x - 2;
    if (tid < 128) A->w3s[tid] = W3c[tid];
    const int l = tid & 127, r0 = tid >> 7;    // one thread per (row, l); r0 in 0..3
    for (int ci = 0; ci < 2; ++ci) {
      const int c = 2 * wkr + ci;
      const int b = c >> 6, q0 = (c & 63) * 4;
      if (tid == 0) {
        while (__hip_atomic_load(&prog[b >> 2], __ATOMIC_RELAXED, __HIP_MEMORY_SCOPE_AGENT) < q0 + 4)
          __builtin_amdgcn_s_sleep(16);
      }
      __syncthreads();   // wakes block; also orders w3s (ci=0) and ends prev chunk's sc reads (ci=1)
      const int row = b * 256 + q0 + r0;
      const float xv = __hip_atomic_load(&xf[row * 128 + l], __ATOMIC_RELAXED, __HIP_MEMORY_SCOPE_AGENT);
      A->xr[r0][l] = xv;
      out[row * 256 + l] = xv;
      __syncthreads();
      // ---- qproj: qp[r0][l] ----
      float qa = b2c[l];
      for (int d = 0; d < 128; d += 4) {
        float4 x4 = *(const float4*)&A->xr[r0][d];
        qa += x4.x * W2c[(d + 0) * 128 + l] + x4.y * W2c[(d + 1) * 128 + l]
            + x4.z * W2c[(d + 2) * 128 + l] + x4.w * W2c[(d + 3) * 128 + l];
      }
      A->qp[r0][l] = qa;
      const float b3v = b3c[0];
      // ---- scores: thread owns k = l + 128j, j=0..3 ----
      float acc0 = b3v, acc1 = b3v, acc2 = b3v, acc3 = b3v;
      const float* keysT = ws + KEYS_OFF + b * (128 * 512);
      for (int cc = 0; cc < 128; cc += 8) {
        __syncthreads();   // kc reuse fence (1st iter: also publishes qp)
        for (int i = tid; i < 8 * 512; i += 512)
          A->kc[i >> 9][i & 511] = keysT[(cc + (i >> 9)) * 512 + (i & 511)];
        __syncthreads();
        for (int lp = 0; lp < 8; ++lp) {
          const float qv = A->qp[r0][cc + lp];  // broadcast
          const float wv = A->w3s[cc + lp];     // broadcast
          acc0 += fast_tanh(A->kc[lp][l]       + qv) * wv;
          acc1 += fast_tanh(A->kc[lp][l + 128] + qv) * wv;
          acc2 += fast_tanh(A->kc[lp][l + 256] + qv) * wv;
          acc3 += fast_tanh(A->kc[lp][l + 384] + qv) * wv;
        }
      }
      A->sc[r0][l]       = acc0;
      A->sc[r0][l + 128] = acc1;
      A->sc[r0][l + 256] = acc2;
      A->sc[r0][l + 384] = acc3;
      __syncthreads();
      // ---- softmax: wave w owns row w (waves 4-7 idle briefly) ----
      {
        const int wave = tid >> 6, lane = tid & 63;
        if (wave < 4) {
          float v[8];
#pragma unroll
          for (int i = 0; i < 8; ++i) v[i] = A->sc[wave][lane + i * 64];
          float m = v[0];
#pragma unroll
          for (int i = 1; i < 8; ++i) m = fmaxf(m, v[i]);
#pragma unroll
          for (int off = 32; off > 0; off >>= 1) m = fmaxf(m, __shfl_xor(m, off));
          float e[8], s = 0.f;
#pragma unroll
          for (int i = 0; i < 8; ++i) { e[i] = __expf(v[i] - m); s += e[i]; }
#pragma unroll
          for (int off = 32; off > 0; off >>= 1) s += __shfl_xor(s, off);
          const float inv = fast_rcp(s);
#pragma unroll
          for (int i = 0; i < 8; ++i) A->sc[wave][lane + i * 64] = e[i] * inv;
        }
      }
      __syncthreads();
      // ---- weighted sum + concat ----
      const float* attb = att + b * (512 * 128);
      float wa = 0.f;
      for (int k = 0; k < 512; k += 4) {
        float4 p4 = *(const float4*)&A->sc[r0][k];
        wa += p4.x * attb[(k + 0) * 128 + l] + p4.y * attb[(k + 1) * 128 + l]
            + p4.z * attb[(k + 2) * 128 + l] + p4.w * attb[(k + 3) * 128 + l];
      }
      out[row * 256 + 128 + l] = wa;
    }
    return;
  }

  // ================= LSTM scan producer =================
  ScanS* S = (ScanS*)smem;
  const _Float16* xz16 = (const _Float16*)(ws + XZ_OFF);
  const int b_base = blockIdx.x * 4;
  const int w = tid >> 6, lane = tid & 63;
  const int q = lane >> 4, p = lane & 15;
  const int b = p & 3, isel = p >> 2;
  const int u = 16 * w + 4 * isel + q;
  const int bg = b_base + b;

  f16x8 afr[4][4];
#pragma unroll
  for (int i = 0; i < 4; ++i) {
    const int col = (p & 3) * 128 + 16 * w + 4 * i + (p >> 2);
#pragma unroll
    for (int kt = 0; kt < 4; ++kt)
#pragma unroll
      for (int j = 0; j < 8; ++j)
        afr[i][kt][j] = (_Float16)Wrf[(kt * 32 + q * 8 + j) * 512 + col];
  }
  {
    _Float16* hp = &S->hb[0][0];
    for (int i = tid; i < 2 * 576; i += 512) hp[i] = (_Float16)0.f;
  }
  const fx4 zeroC = {0.f, 0.f, 0.f, 0.f};
  float cst = 0.f, hval = 0.f;
  const _Float16* xp = xz16 + (bg * 128 + u) * 4;
  uint2 pf0 = *(const uint2*)(xp);
  uint2 pf1 = *(const uint2*)(xp + 4096);
  uint2 pf2 = *(const uint2*)(xp + 8192);
  __syncthreads();

  const int brow = b * 144;  // stride 144: banks 8b+4q(+2isel) -> 2-way (free)
  for (int t = 0; t < 256; ++t) {
    const _Float16* hrow = &S->hb[t & 1][brow];
    f16x8 bfr[4];
#pragma unroll
    for (int kt = 0; kt < 4; ++kt)
      bfr[kt] = *(const f16x8*)&hrow[kt * 32 + q * 8];
    fx4 acc[4];
#pragma unroll
    for (int i = 0; i < 4; ++i)
      acc[i] = __builtin_amdgcn_mfma_f32_16x16x32_f16(afr[i][0], bfr[0], zeroC, 0, 0, 0);
#pragma unroll
    for (int kt = 1; kt < 4; ++kt)
#pragma unroll
      for (int i = 0; i < 4; ++i)
        acc[i] = __builtin_amdgcn_mfma_f32_16x16x32_f16(afr[i][kt], bfr[kt], acc[i], 0, 0, 0);

    float z[4];
#pragma unroll
    for (int r = 0; r < 4; ++r) {
      float s01 = (isel & 1) ? acc[1][r] : acc[0][r];
      float s23 = (isel & 1) ? acc[3][r] : acc[2][r];
      z[r] = (isel & 2) ? s23 : s01;
    }

    uint2 cur = pf0;
    pf0 = pf1; pf1 = pf2;

    const _Float16* cf = (const _Float16*)&cur;
    const float zi = z[0] + (float)cf[0];
    const float zf = z[1] + (float)cf[1];
    const float zg = z[2] + (float)cf[2];
    const float zo = z[3] + (float)cf[3];
    cst = fast_sig(zf) * cst + fast_sig(zi) * fast_tanh(zg);
    hval = fast_sig(zo) * fast_tanh(cst);
    S->hb[(t + 1) & 1][brow + u] = (_Float16)hval;
    // agent-scope write-through so consumers on other XCDs see fresh data
    __hip_atomic_store(&xf[(bg * 256 + t) * 128 + u], hval,
                       __ATOMIC_RELAXED, __HIP_MEMORY_SCOPE_AGENT);

    if ((t & 15) == 15) {
      __syncthreads();  // drains vmcnt(0) for ALL waves -> x rows <= t globally visible
      if (tid == 0)
        __hip_atomic_store(&prog[blockIdx.x], t + 1,
                           __ATOMIC_RELAXED, __HIP_MEMORY_SCOPE_AGENT);
    } else {
      LDS_BARRIER();  // LDS visibility only; no vmcnt drain
    }
    // issue prefetch AFTER the barrier so publication vmcnt(0) doesn't wait on it
    const int t3 = (t + 3 < 256) ? t + 3 : 255;
    pf2 = *(const uint2*)(xp + t3 * 4096);
  }
  out[OUT_H + bg * 128 + u] = hval;
  out[OUT_C + bg * 128 + u] = cst;
}

extern "C" void kernel_launch(void* const* d_in, const int* in_sizes, int n_in,
                              void* d_out, int out_size, void* d_ws, size_t ws_size,
                              hipStream_t stream) {
  const float* inputs   = (const float*)d_in[0];
  const float* attended = (const float*)d_in[1];
  const float* Wk       = (const float*)d_in[2];
  const float* Wr       = (const float*)d_in[3];
  const float* bias     = (const float*)d_in[4];
  const float* W1       = (const float*)d_in[5];
  const float* b1       = (const float*)d_in[6];
  const float* W2       = (const float*)d_in[7];
  const float* b2       = (const float*)d_in[8];
  const float* W3       = (const float*)d_in[9];
  const float* b3       = (const float*)d_in[10];
  float* out = (float*)d_out;
  float* ws = (float*)d_ws;

  hipLaunchKernelGGL(prologue_k, dim3(512), dim3(256), 0, stream,
                     inputs, Wk, bias, attended, W1, b1, ws);
  hipLaunchKernelGGL(fused_scan_attn, dim3(258), dim3(512), 0, stream,
                     Wr, attended, W2, b2, W3, b3, ws, out);
}

// Round 3
// 329.611 us; speedup vs baseline: 2.0546x; 1.0469x over previous
//
#include <hip/hip_runtime.h>
#include <hip/hip_bf16.h>

// Problem: B=8, T_OUT=256, T_IN=512, L=128, D_IN=128, D_ATT=128 (f32 in/out).
// R10: fusion kept (R9 structure). Three changes from counter post-mortem:
//  (1) Worker pairing {w, 511-w}, earlier-q0 first. R9's {2w,2w+1} put both
//      late chunks of a pair on the SAME worker -> post-scan tail = 2 serial
//      chunks (~55us). Now the 64 final-window chunks sit on 64 distinct
//      workers -> tail = 1 chunk.
//  (2) Score loop algebra: prescale kc,qp by C=-2*log2e, stage w3s=2*w3,
//      acc += rcp(1+exp2(k'+q'))*w3s, correct once with (b3 - sum(w3)).
//      9 -> 6 inst/element (VALUBusy-derived chunk cost was 21us, 3x my
//      estimate; the two unfoldable muls per tanh were a third of it).
//  (3) Scan-CU hygiene: grid 260 with no-op blocks 256/257 (round-robin puts
//      them exactly on the scan CUs; they exit instantly), s_setprio(1) on
//      scan waves, publication cadence 16->32 (halves vmcnt(0) drains).
// Scan core itself is byte-identical to R9 (verified: conflicts 0, no spill).
//
// ws layout (float elements):
#define XF_OFF   0         // f32 x[8*256*128]
#define PROG_OFF 524288    // int prog[2]
#define XZ_OFF   1048576   // f16[8*256*512] region (2 MB)
#define KEYS_OFF 2097152   // f32 keysT[8][128][512]
// out layout (f32): out(8,256,256) @0, h(8,128) @524288, c(8,128) @525312
#define OUT_H    524288
#define OUT_C    525312

#define LDS_BARRIER() __asm__ __volatile__("s_waitcnt lgkmcnt(0)\n\ts_barrier" ::: "memory")

#if __has_builtin(__builtin_amdgcn_exp2f)
#define EXP2F __builtin_amdgcn_exp2f
#else
#define EXP2F exp2f
#endif

typedef _Float16 f16x8 __attribute__((ext_vector_type(8)));
typedef float fx4 __attribute__((ext_vector_type(4)));

__device__ __forceinline__ float fast_rcp(float x) { return __builtin_amdgcn_rcpf(x); }
__device__ __forceinline__ float fast_sig(float v) { return fast_rcp(1.f + __expf(-v)); }
__device__ __forceinline__ float fast_tanh(float v) { return 2.f * fast_rcp(1.f + __expf(-2.f * v)) - 1.f; }

// C = -2*log2(e): tanh(v) = 2*rcp(1+exp2(C*v)) - 1
#define CSCALE (-2.8853900817779268f)

// ---------------- Kernel 1: xz prologue (blocks 0-255) + keysT GEMM (256-511) ----------------
__global__ __launch_bounds__(256)
void prologue_k(const float* __restrict__ inp, const float* __restrict__ Wk,
                const float* __restrict__ bias, const float* __restrict__ att,
                const float* __restrict__ W1, const float* __restrict__ b1,
                float* __restrict__ ws) {
  __shared__ float ar[8][128];
  __shared__ float ar2[16][128];
  const int tid = threadIdx.x;

  if (blockIdx.x < 256) {
    // ---- xz = inputs @ Wk + bias, f16 [t][b][u][gate] ----
    _Float16* xz16 = (_Float16*)(ws + XZ_OFF);
    const int row0 = blockIdx.x * 8;
    for (int i = tid; i < 8 * 128; i += 256) ar[i >> 7][i & 127] = inp[row0 * 128 + i];
    __syncthreads();
    float acc[8][2];
    const float bb0 = bias[tid], bb1 = bias[tid + 256];
#pragma unroll
    for (int r = 0; r < 8; ++r) { acc[r][0] = bb0; acc[r][1] = bb1; }
    for (int d = 0; d < 128; d += 4) {
      float w0a = Wk[(d + 0) * 512 + tid], w0b = Wk[(d + 0) * 512 + tid + 256];
      float w1a = Wk[(d + 1) * 512 + tid], w1b = Wk[(d + 1) * 512 + tid + 256];
      float w2a = Wk[(d + 2) * 512 + tid], w2b = Wk[(d + 2) * 512 + tid + 256];
      float w3a = Wk[(d + 3) * 512 + tid], w3b = Wk[(d + 3) * 512 + tid + 256];
#pragma unroll
      for (int r = 0; r < 8; ++r) {
        float4 a4 = *(const float4*)&ar[r][d];
        acc[r][0] += a4.x * w0a + a4.y * w1a + a4.z * w2a + a4.w * w3a;
        acc[r][1] += a4.x * w0b + a4.y * w1b + a4.z * w2b + a4.w * w3b;
      }
    }
    const int u = tid & 127, g0 = tid >> 7;
#pragma unroll
    for (int r = 0; r < 8; ++r) {
      const int row = row0 + r, b = row >> 8, t = row & 255;
      const int base = ((t * 8 + b) * 128 + u) * 4;
      xz16[base + g0]     = (_Float16)acc[r][0];
      xz16[base + g0 + 2] = (_Float16)acc[r][1];
    }
    return;
  }

  // ---- keysT[b][l][k] = (attended @ W1 + b1)^T : 16 k-rows per block ----
  if (blockIdx.x == 256 && tid < 2) ((int*)(ws + PROG_OFF))[tid] = 0;  // reset flags each iteration
  const int kb = blockIdx.x - 256;
  const int row0 = kb * 16;              // global row in (b*512 + k)
  const int bq = row0 >> 9, k0 = row0 & 511;
  for (int i = tid; i < 16 * 128; i += 256) ar2[i >> 7][i & 127] = att[row0 * 128 + i];
  __syncthreads();
  const int l = tid & 127, r0 = tid >> 7;  // r0 in 0..1
  float acc[8];
  const float bl = b1[l];
#pragma unroll
  for (int i = 0; i < 8; ++i) acc[i] = bl;
  for (int d = 0; d < 128; d += 4) {
    float w0 = W1[(d + 0) * 128 + l], w1 = W1[(d + 1) * 128 + l];
    float w2 = W1[(d + 2) * 128 + l], w3 = W1[(d + 3) * 128 + l];
#pragma unroll
    for (int i = 0; i < 8; ++i) {
      float4 a4 = *(const float4*)&ar2[r0 * 8 + i][d];
      acc[i] += a4.x * w0 + a4.y * w1 + a4.z * w2 + a4.w * w3;
    }
  }
  float* kT = ws + KEYS_OFF + (bq * 128 + l) * 512 + k0 + r0 * 8;
  float4 lo = {acc[0], acc[1], acc[2], acc[3]};
  float4 hi = {acc[4], acc[5], acc[6], acc[7]};
  *(float4*)kT = lo;
  *(float4*)(kT + 4) = hi;
}

// ---------------- Kernel 2: fused LSTM scan (blocks 0-1) + attention workers ----------------
struct ScanS { _Float16 hb[2][576]; };                       // 2.25 KB
struct AttnS {                                               // 29312 B total
  float xr[4][128];       // staged x rows
  float qp[4][128];       // q projection (prescaled by CSCALE)
  float sc[4][512];       // scores -> probs
  float kc[8][516];       // keysT chunk (prescaled by CSCALE)
  float w3s[128];         // 2*W3
};

__global__ __launch_bounds__(512)
void fused_scan_attn(const float* __restrict__ Wrf, const float* __restrict__ att,
                     const float* __restrict__ W2c, const float* __restrict__ b2c,
                     const float* __restrict__ W3c, const float* __restrict__ b3c,
                     float* __restrict__ ws, float* __restrict__ out) {
  __shared__ __align__(16) char smem[29312];
  const int tid = threadIdx.x;
  int* prog = (int*)(ws + PROG_OFF);
  float* xf = ws + XF_OFF;

  if (blockIdx.x == 256 || blockIdx.x == 257) return;  // placement shims for the scan CUs

  if (blockIdx.x >= 2) {
    // ================= attention worker: chunks {w, 511-w}, earlier q0 first =================
    AttnS* A = (AttnS*)smem;
    const int wkr = (blockIdx.x < 256) ? (int)blockIdx.x - 2 : (int)blockIdx.x - 4;  // 0..255
    int cA = wkr, cB = 511 - wkr;
    if ((cA & 63) > (cB & 63)) { int tmp = cA; cA = cB; cB = tmp; }
    if (tid < 128) A->w3s[tid] = 2.f * W3c[tid];
    // sum(w3) for the tanh->rcp correction (once; W3 is L2-hot)
    float sw3 = 0.f;
    for (int ll = 0; ll < 128; ll += 4) {
      float4 w4 = *(const float4*)&W3c[ll];
      sw3 += w4.x + w4.y + w4.z + w4.w;
    }
    const int l = tid & 127, r0 = tid >> 7;    // one thread per (row, l); r0 in 0..3
    for (int ci = 0; ci < 2; ++ci) {
      const int c = ci ? cB : cA;
      const int b = c >> 6, q0 = (c & 63) * 4;
      if (tid == 0) {
        while (__hip_atomic_load(&prog[b >> 2], __ATOMIC_RELAXED, __HIP_MEMORY_SCOPE_AGENT) < q0 + 4)
          __builtin_amdgcn_s_sleep(16);
      }
      __syncthreads();   // wake barrier; also orders w3s (ci=0) / prev chunk's sc reads (ci=1)
      const int row = b * 256 + q0 + r0;
      const float xv = __hip_atomic_load(&xf[row * 128 + l], __ATOMIC_RELAXED, __HIP_MEMORY_SCOPE_AGENT);
      A->xr[r0][l] = xv;
      out[row * 256 + l] = xv;
      __syncthreads();
      // ---- qproj (prescaled): qp[r0][l] = CSCALE*(x@W2 + b2) ----
      float qa = b2c[l];
      for (int d = 0; d < 128; d += 4) {
        float4 x4 = *(const float4*)&A->xr[r0][d];
        qa += x4.x * W2c[(d + 0) * 128 + l] + x4.y * W2c[(d + 1) * 128 + l]
            + x4.z * W2c[(d + 2) * 128 + l] + x4.w * W2c[(d + 3) * 128 + l];
      }
      A->qp[r0][l] = CSCALE * qa;
      const float base = b3c[0] - sw3;   // b3 + sum_l(-w3): tanh = 2r-1 correction
      // ---- scores: thread owns k = l + 128j, j=0..3 ----
      float acc0 = base, acc1 = base, acc2 = base, acc3 = base;
      const float* keysT = ws + KEYS_OFF + b * (128 * 512);
      for (int cc = 0; cc < 128; cc += 8) {
        __syncthreads();   // kc reuse fence (1st iter: also publishes qp)
        for (int i = tid; i < 8 * 512; i += 512)
          A->kc[i >> 9][i & 511] = CSCALE * keysT[(cc + (i >> 9)) * 512 + (i & 511)];
        __syncthreads();
        for (int lp = 0; lp < 8; ++lp) {
          const float qv = A->qp[r0][cc + lp];  // broadcast
          const float wv = A->w3s[cc + lp];     // broadcast, = 2*w3
          acc0 += fast_rcp(1.f + EXP2F(A->kc[lp][l]       + qv)) * wv;
          acc1 += fast_rcp(1.f + EXP2F(A->kc[lp][l + 128] + qv)) * wv;
          acc2 += fast_rcp(1.f + EXP2F(A->kc[lp][l + 256] + qv)) * wv;
          acc3 += fast_rcp(1.f + EXP2F(A->kc[lp][l + 384] + qv)) * wv;
        }
      }
      A->sc[r0][l]       = acc0;
      A->sc[r0][l + 128] = acc1;
      A->sc[r0][l + 256] = acc2;
      A->sc[r0][l + 384] = acc3;
      __syncthreads();
      // ---- softmax: wave w owns row w (waves 4-7 idle briefly) ----
      {
        const int wave = tid >> 6, lane = tid & 63;
        if (wave < 4) {
          float v[8];
#pragma unroll
          for (int i = 0; i < 8; ++i) v[i] = A->sc[wave][lane + i * 64];
          float m = v[0];
#pragma unroll
          for (int i = 1; i < 8; ++i) m = fmaxf(m, v[i]);
#pragma unroll
          for (int off = 32; off > 0; off >>= 1) m = fmaxf(m, __shfl_xor(m, off));
          float e[8], s = 0.f;
#pragma unroll
          for (int i = 0; i < 8; ++i) { e[i] = __expf(v[i] - m); s += e[i]; }
#pragma unroll
          for (int off = 32; off > 0; off >>= 1) s += __shfl_xor(s, off);
          const float inv = fast_rcp(s);
#pragma unroll
          for (int i = 0; i < 8; ++i) A->sc[wave][lane + i * 64] = e[i] * inv;
        }
      }
      __syncthreads();
      // ---- weighted sum + concat ----
      const float* attb = att + b * (512 * 128);
      float wa = 0.f;
      for (int k = 0; k < 512; k += 4) {
        float4 p4 = *(const float4*)&A->sc[r0][k];
        wa += p4.x * attb[(k + 0) * 128 + l] + p4.y * attb[(k + 1) * 128 + l]
            + p4.z * attb[(k + 2) * 128 + l] + p4.w * attb[(k + 3) * 128 + l];
      }
      out[row * 256 + 128 + l] = wa;
    }
    return;
  }

  // ================= LSTM scan producer =================
  __builtin_amdgcn_s_setprio(1);  // scan is the critical path; outrank any co-resident wave
  ScanS* S = (ScanS*)smem;
  const _Float16* xz16 = (const _Float16*)(ws + XZ_OFF);
  const int b_base = blockIdx.x * 4;
  const int w = tid >> 6, lane = tid & 63;
  const int q = lane >> 4, p = lane & 15;
  const int b = p & 3, isel = p >> 2;
  const int u = 16 * w + 4 * isel + q;
  const int bg = b_base + b;

  f16x8 afr[4][4];
#pragma unroll
  for (int i = 0; i < 4; ++i) {
    const int col = (p & 3) * 128 + 16 * w + 4 * i + (p >> 2);
#pragma unroll
    for (int kt = 0; kt < 4; ++kt)
#pragma unroll
      for (int j = 0; j < 8; ++j)
        afr[i][kt][j] = (_Float16)Wrf[(kt * 32 + q * 8 + j) * 512 + col];
  }
  {
    _Float16* hp = &S->hb[0][0];
    for (int i = tid; i < 2 * 576; i += 512) hp[i] = (_Float16)0.f;
  }
  const fx4 zeroC = {0.f, 0.f, 0.f, 0.f};
  float cst = 0.f, hval = 0.f;
  const _Float16* xp = xz16 + (bg * 128 + u) * 4;
  uint2 pf0 = *(const uint2*)(xp);
  uint2 pf1 = *(const uint2*)(xp + 4096);
  uint2 pf2 = *(const uint2*)(xp + 8192);
  __syncthreads();

  const int brow = b * 144;  // stride 144: banks 8b+4q(+2isel) -> 2-way (free)
  for (int t = 0; t < 256; ++t) {
    const _Float16* hrow = &S->hb[t & 1][brow];
    f16x8 bfr[4];
#pragma unroll
    for (int kt = 0; kt < 4; ++kt)
      bfr[kt] = *(const f16x8*)&hrow[kt * 32 + q * 8];
    fx4 acc[4];
#pragma unroll
    for (int i = 0; i < 4; ++i)
      acc[i] = __builtin_amdgcn_mfma_f32_16x16x32_f16(afr[i][0], bfr[0], zeroC, 0, 0, 0);
#pragma unroll
    for (int kt = 1; kt < 4; ++kt)
#pragma unroll
      for (int i = 0; i < 4; ++i)
        acc[i] = __builtin_amdgcn_mfma_f32_16x16x32_f16(afr[i][kt], bfr[kt], acc[i], 0, 0, 0);

    float z[4];
#pragma unroll
    for (int r = 0; r < 4; ++r) {
      float s01 = (isel & 1) ? acc[1][r] : acc[0][r];
      float s23 = (isel & 1) ? acc[3][r] : acc[2][r];
      z[r] = (isel & 2) ? s23 : s01;
    }

    uint2 cur = pf0;
    pf0 = pf1; pf1 = pf2;

    const _Float16* cf = (const _Float16*)&cur;
    const float zi = z[0] + (float)cf[0];
    const float zf = z[1] + (float)cf[1];
    const float zg = z[2] + (float)cf[2];
    const float zo = z[3] + (float)cf[3];
    cst = fast_sig(zf) * cst + fast_sig(zi) * fast_tanh(zg);
    hval = fast_sig(zo) * fast_tanh(cst);
    S->hb[(t + 1) & 1][brow + u] = (_Float16)hval;
    // agent-scope write-through so consumers on other XCDs see fresh data
    __hip_atomic_store(&xf[(bg * 256 + t) * 128 + u], hval,
                       __ATOMIC_RELAXED, __HIP_MEMORY_SCOPE_AGENT);

    if ((t & 31) == 31) {
      __syncthreads();  // drains vmcnt(0) for ALL waves -> x rows <= t globally visible
      if (tid == 0)
        __hip_atomic_store(&prog[blockIdx.x], t + 1,
                           __ATOMIC_RELAXED, __HIP_MEMORY_SCOPE_AGENT);
    } else {
      LDS_BARRIER();  // LDS visibility only; no vmcnt drain
    }
    // issue prefetch AFTER the barrier so publication vmcnt(0) doesn't wait on it
    const int t3 = (t + 3 < 256) ? t + 3 : 255;
    pf2 = *(const uint2*)(xp + t3 * 4096);
  }
  out[OUT_H + bg * 128 + u] = hval;
  out[OUT_C + bg * 128 + u] = cst;
}

extern "C" void kernel_launch(void* const* d_in, const int* in_sizes, int n_in,
                              void* d_out, int out_size, void* d_ws, size_t ws_size,
                              hipStream_t stream) {
  const float* inputs   = (const float*)d_in[0];
  const float* attended = (const float*)d_in[1];
  const float* Wk       = (const float*)d_in[2];
  const float* Wr       = (const float*)d_in[3];
  const float* bias     = (const float*)d_in[4];
  const float* W1       = (const float*)d_in[5];
  const float* b1       = (const float*)d_in[6];
  const float* W2       = (const float*)d_in[7];
  const float* b2       = (const float*)d_in[8];
  const float* W3       = (const float*)d_in[9];
  const float* b3       = (const float*)d_in[10];
  float* out = (float*)d_out;
  float* ws = (float*)d_ws;

  hipLaunchKernelGGL(prologue_k, dim3(512), dim3(256), 0, stream,
                     inputs, Wk, bias, attended, W1, b1, ws);
  hipLaunchKernelGGL(fused_scan_attn, dim3(260), dim3(512), 0, stream,
                     Wr, attended, W2, b2, W3, b3, ws, out);
}